// Round 5
// baseline (367.537 us; speedup 1.0000x reference)
//
#include <hip/hip_runtime.h>
#include <hip/hip_bf16.h>
#include <stdint.h>

typedef unsigned short u16;
typedef __attribute__((ext_vector_type(8))) __bf16 bf16x8;
typedef __attribute__((ext_vector_type(4))) float f32x4;
typedef __attribute__((ext_vector_type(8))) unsigned short u16x8;
typedef __attribute__((ext_vector_type(4))) unsigned int u32x4;

static __device__ __forceinline__ u16 f2bf(float x) {
  __hip_bfloat16 h = __float2bfloat16(x);
  u16 u;
  __builtin_memcpy(&u, &h, 2);
  return u;
}

static __device__ __forceinline__ float fast_tanh(float x) {
  float e = __expf(2.0f * x);
  return 1.0f - 2.0f * __builtin_amdgcn_rcpf(e + 1.0f);
}

static __device__ __forceinline__ void gload_lds16(const void* g, void* l) {
  __builtin_amdgcn_global_load_lds(
      (const __attribute__((address_space(1))) unsigned int*)g,
      (__attribute__((address_space(3))) unsigned int*)l, 16, 0, 0);
}

// XOR swizzle for 128-B rows (reg-staged kernels)
static __device__ __forceinline__ int swz(int row, int byte_in_row) {
  return row * 128 + (byte_in_row ^ ((row & 7) << 4));
}

// ---------------------------------------------------------------------------
// Transpose + cast: out[n][k] (bf16) = in[k][n] (f32).  grid = N blocks.
// ---------------------------------------------------------------------------
__global__ __launch_bounds__(256) void transpose_cast_kernel(
    const float* __restrict__ in, u16* __restrict__ out, int K, int N) {
  int n = blockIdx.x;
  for (int k = threadIdx.x; k < K; k += 256) {
    out[(size_t)n * K + k] = f2bf(in[(size_t)k * N + n]);
  }
}

// ---------------------------------------------------------------------------
// Linear: out[M][640] = A[M][512] @ W + bias (W transposed bf16 [640][512]).
// ---------------------------------------------------------------------------
__global__ __launch_bounds__(256) void linear_kernel(
    const float* __restrict__ A, const u16* __restrict__ Wt,
    const float* __restrict__ bias, float* __restrict__ out) {
  __shared__ u16 sA[64 * 64];
  __shared__ u16 sB[64 * 64];
  const int t = threadIdx.x;
  const int bx = blockIdx.x;
  const int m0 = (bx / 10) * 64;
  const int n0 = (bx % 10) * 64;
  const int lane = t & 63, wid = t >> 6;
  const int wr = wid >> 1, wc = wid & 1;
  const int l15 = lane & 15, lk8 = (lane >> 4) << 3;

  const int srow = t >> 2;
  const int kc = (t & 3) << 4;

  f32x4 acc[2][2] = {};

  for (int k0 = 0; k0 < 512; k0 += 64) {
    {
      const float4* gp = (const float4*)(A + (size_t)(m0 + srow) * 512 + k0 + kc);
      u16 tmp[16];
#pragma unroll
      for (int i = 0; i < 4; ++i) {
        float4 v = gp[i];
        tmp[i * 4 + 0] = f2bf(v.x);
        tmp[i * 4 + 1] = f2bf(v.y);
        tmp[i * 4 + 2] = f2bf(v.z);
        tmp[i * 4 + 3] = f2bf(v.w);
      }
      *(u16x8*)((char*)sA + swz(srow, kc * 2)) = *(u16x8*)&tmp[0];
      *(u16x8*)((char*)sA + swz(srow, kc * 2 + 16)) = *(u16x8*)&tmp[8];
    }
    {
      const int off = (t & 3) << 5;
      const char* gsrc = (const char*)Wt + ((size_t)(n0 + srow) * 512 + k0) * 2 + off;
      u32x4 q0 = *(const u32x4*)gsrc;
      u32x4 q1 = *(const u32x4*)(gsrc + 16);
      *(u32x4*)((char*)sB + swz(srow, off)) = q0;
      *(u32x4*)((char*)sB + swz(srow, off + 16)) = q1;
    }
    __syncthreads();
#pragma unroll
    for (int kh = 0; kh < 2; ++kh) {
      const int kbyte = kh * 64 + lk8 * 2;
      bf16x8 av[2], bv[2];
#pragma unroll
      for (int mf = 0; mf < 2; ++mf)
        av[mf] = *(const bf16x8*)((char*)sA + swz(wr * 32 + mf * 16 + l15, kbyte));
#pragma unroll
      for (int nf = 0; nf < 2; ++nf)
        bv[nf] = *(const bf16x8*)((char*)sB + swz(wc * 32 + nf * 16 + l15, kbyte));
#pragma unroll
      for (int mf = 0; mf < 2; ++mf)
#pragma unroll
        for (int nf = 0; nf < 2; ++nf)
          acc[mf][nf] = __builtin_amdgcn_mfma_f32_16x16x32_bf16(
              av[mf], bv[nf], acc[mf][nf], 0, 0, 0);
    }
    __syncthreads();
  }

  const int r4 = (lane >> 4) << 2;
#pragma unroll
  for (int nf = 0; nf < 2; ++nf) {
    const int nc = n0 + wc * 32 + nf * 16 + l15;
    const float bjv = bias[nc];
#pragma unroll
    for (int mf = 0; mf < 2; ++mf) {
      const int mr = m0 + wr * 32 + mf * 16 + r4;
#pragma unroll
      for (int r = 0; r < 4; ++r)
        out[(size_t)(mr + r) * 640 + nc] = acc[mf][nf][r] + bjv;
    }
  }
}

// ---------------------------------------------------------------------------
// Joint materialize: joint[row][k] (bf16) = tanh(f[bt][k] + g[b][u][k])
// ---------------------------------------------------------------------------
__global__ __launch_bounds__(256) void joint_kernel(
    const float* __restrict__ f, const float* __restrict__ g,
    u16* __restrict__ joint, int m_base) {
  int idx = blockIdx.x * 256 + threadIdx.x;
  int row = idx / 80;
  int kc = (idx % 80) * 8;
  int m = m_base + row;
  int bt = m >> 7;
  int b = bt >> 8;
  int u = m & 127;
  const float4* fp = (const float4*)(f + (size_t)bt * 640 + kc);
  const float4* gp = (const float4*)(g + ((size_t)(b * 128 + u)) * 640 + kc);
  u16 tmp[8];
#pragma unroll
  for (int i = 0; i < 2; ++i) {
    float4 fv = fp[i];
    float4 gv = gp[i];
    tmp[i * 4 + 0] = f2bf(fast_tanh(fv.x + gv.x));
    tmp[i * 4 + 1] = f2bf(fast_tanh(fv.y + gv.y));
    tmp[i * 4 + 2] = f2bf(fast_tanh(fv.z + gv.z));
    tmp[i * 4 + 3] = f2bf(fast_tanh(fv.w + gv.w));
  }
  *(u16x8*)(joint + (size_t)row * 640 + kc) = *(u16x8*)&tmp[0];
}

// ---------------------------------------------------------------------------
// 256x256 deep-pipelined GEMM (T3+T4): out[m][v] = joint[m]@Wjt[v] + bias.
// BK=32, 4 LDS slots (4x32KiB), 3 K-tiles prefetched ahead, counted
// s_waitcnt vmcnt(8) (never 0 in loop), ONE raw s_barrier per K-tile,
// setprio around MFMA (T5), m204 XCD swizzle (T1), 2-way-free LDS XOR
// swizzle for 64-B rows (T2, both-sides: inverse on global src + on read).
// 512 threads, 8 waves (2Mx4N), wave-tile 128x64.  grid.x = mtiles*4.
// ---------------------------------------------------------------------------
__global__ __launch_bounds__(512, 2) void gemm256_kernel(
    const u16* __restrict__ A,    // [R][640] bf16 (chunk of joint)
    const u16* __restrict__ Bt,   // [1024][640] bf16 (W_joint^T)
    const float* __restrict__ bias,
    float* __restrict__ out,      // [131072][1024]
    int m_base, int mtiles) {
  extern __shared__ char smem[];  // 4 slots x (A 16K | B 16K) = 131072 B
  const int t = threadIdx.x;
  const int lane = t & 63, wid = t >> 6;

  // m204 bijective XCD-chunked swizzle
  const int nwg = mtiles * 4;
  const int bid = blockIdx.x;
  const int q = nwg >> 3, r = nwg & 7;
  const int xcd = bid & 7, local = bid >> 3;
  const int wgid = (xcd < r ? xcd * (q + 1) : r * (q + 1) + (xcd - r) * q) + local;
  const int mt = wgid >> 2, nt = wgid & 3;

  const int wr = wid >> 2, wc = wid & 3;  // wave-tile rows wr*128, cols wc*64
  const int l15 = lane & 15;
  // read-side swizzle: col-16B-slot = (lane>>4) ^ ((row>>1)&3); fragment row
  // bases are multiples of 16 so (row>>1)&3 == (l15>>1)&3 (lane-invariant).
  const int colbyte = (((lane >> 4) ^ ((l15 >> 1) & 3)) << 4);

  // staging: per K-tile, thread t loads rows wid*16 + (lane>>2) (+128 for j=1)
  // with inverse-swizzled source column so linear gload_lds dest yields the
  // swizzled layout (rule 21 / m173).
  const int srow = lane >> 2;
  const int scol = ((lane & 3) ^ ((lane >> 3) & 3)) << 3;  // element offset
  const u16* aS = A + (size_t)(mt * 256 + wid * 16 + srow) * 640 + scol;
  const u16* bS = Bt + (size_t)(nt * 256 + wid * 16 + srow) * 640 + scol;
  const int ldsbase = wid * 1024;  // wave-uniform dest offset within section

#define STAGE(kt, slot)                                              \
  do {                                                               \
    const int ko_ = (kt) * 32;                                       \
    char* sb_ = smem + (slot) * 32768;                               \
    gload_lds16(aS + ko_, sb_ + ldsbase);                            \
    gload_lds16(aS + 128 * 640 + ko_, sb_ + 8192 + ldsbase);         \
    gload_lds16(bS + ko_, sb_ + 16384 + ldsbase);                    \
    gload_lds16(bS + 128 * 640 + ko_, sb_ + 24576 + ldsbase);        \
  } while (0)

  f32x4 acc[8][4] = {};

  // prologue: stage tiles 0,1,2 into slots 0,1,2
  STAGE(0, 0);
  STAGE(1, 1);
  STAGE(2, 2);

  for (int tt = 0; tt < 20; ++tt) {
    // counted wait: tiles tt+1, tt+2 (8 loads) may stay in flight; tile tt
    // is certified landed.  NEVER vmcnt(0) in the loop (T4).
    asm volatile("s_waitcnt vmcnt(8)" ::: "memory");
    __builtin_amdgcn_s_barrier();
    __builtin_amdgcn_sched_barrier(0);
    // stage tile tt+3 into the slot freed by tile tt-1 (barrier above
    // certifies all waves finished reading it).  Tail: re-stage tile 19
    // into dead slots to keep vmcnt accounting uniform (L2-hot, no HBM).
    const int kt = (tt + 3 > 19) ? 19 : tt + 3;
    STAGE(kt, (tt + 3) & 3);

    const char* sA = smem + (tt & 3) * 32768;
    const char* sB = sA + 16384;
    bf16x8 av[8], bv[4];
#pragma unroll
    for (int nf = 0; nf < 4; ++nf)
      bv[nf] = *(const bf16x8*)(sB + (wc * 64 + nf * 16 + l15) * 64 + colbyte);
#pragma unroll
    for (int mi = 0; mi < 8; ++mi)
      av[mi] = *(const bf16x8*)(sA + (wr * 128 + mi * 16 + l15) * 64 + colbyte);

    __builtin_amdgcn_s_setprio(1);
#pragma unroll
    for (int mi = 0; mi < 8; ++mi)
#pragma unroll
      for (int nf = 0; nf < 4; ++nf)
        acc[mi][nf] = __builtin_amdgcn_mfma_f32_16x16x32_bf16(
            av[mi], bv[nf], acc[mi][nf], 0, 0, 0);
    __builtin_amdgcn_s_setprio(0);
    __builtin_amdgcn_sched_barrier(0);
  }
#undef STAGE

  // epilogue
  const int r4 = (lane >> 4) << 2;
#pragma unroll
  for (int nf = 0; nf < 4; ++nf) {
    const int v = nt * 256 + wc * 64 + nf * 16 + l15;
    const float bjv = bias[v];
#pragma unroll
    for (int mf = 0; mf < 8; ++mf) {
      const size_t m = (size_t)m_base + (size_t)mt * 256 + wr * 128 + mf * 16 + r4;
#pragma unroll
      for (int rr = 0; rr < 4; ++rr)
        out[(m + rr) * 1024 + v] = acc[mf][nf][rr] + bjv;
    }
  }
}

// ---------------------------------------------------------------------------
// Fallback (fused) if ws can't hold the joint buffer.
// ---------------------------------------------------------------------------
__global__ __launch_bounds__(512) void fused_joint_kernel(
    const float* __restrict__ f, const float* __restrict__ g,
    const u16* __restrict__ Wjt, const float* __restrict__ bj,
    float* __restrict__ out) {
  __shared__ u16 sA[128 * 64];
  __shared__ u16 sB[256 * 64];
  const int t = threadIdx.x;
  const int bt = blockIdx.x;
  const int b = bt >> 8;
  const int v0 = blockIdx.y << 8;
  const float* frow = f + (size_t)bt * 640;
  const float* gbase = g + (size_t)b * 128 * 640;

  const int lane = t & 63, wid = t >> 6;
  const int wr = wid >> 2, wc = wid & 3;
  const int l15 = lane & 15, lk8 = (lane >> 4) << 3;

  const int au = t >> 2;
  const int akc = (t & 3) << 4;
  const int bn = t >> 1;
  const int boff = (t & 1) << 6;

  f32x4 acc[4][4] = {};

  for (int k0 = 0; k0 < 640; k0 += 64) {
    {
      const float4* gp = (const float4*)(gbase + (size_t)au * 640 + k0 + akc);
      const float4* fp = (const float4*)(frow + k0 + akc);
      u16 tmp[16];
#pragma unroll
      for (int i = 0; i < 4; ++i) {
        float4 gv = gp[i];
        float4 fv = fp[i];
        tmp[i * 4 + 0] = f2bf(fast_tanh(gv.x + fv.x));
        tmp[i * 4 + 1] = f2bf(fast_tanh(gv.y + fv.y));
        tmp[i * 4 + 2] = f2bf(fast_tanh(gv.z + fv.z));
        tmp[i * 4 + 3] = f2bf(fast_tanh(gv.w + fv.w));
      }
      *(u16x8*)((char*)sA + swz(au, akc * 2)) = *(u16x8*)&tmp[0];
      *(u16x8*)((char*)sA + swz(au, akc * 2 + 16)) = *(u16x8*)&tmp[8];
    }
    {
      const char* gsrc = (const char*)Wjt + ((size_t)(v0 + bn) * 640 + k0) * 2 + boff;
#pragma unroll
      for (int i = 0; i < 4; ++i) {
        u32x4 qv = *(const u32x4*)(gsrc + i * 16);
        *(u32x4*)((char*)sB + swz(bn, boff + i * 16)) = qv;
      }
    }
    __syncthreads();
#pragma unroll
    for (int kh = 0; kh < 2; ++kh) {
      const int kbyte = kh * 64 + lk8 * 2;
      bf16x8 av[4], bv[4];
#pragma unroll
      for (int mf = 0; mf < 4; ++mf)
        av[mf] = *(const bf16x8*)((char*)sA + swz(wr * 64 + mf * 16 + l15, kbyte));
#pragma unroll
      for (int nf = 0; nf < 4; ++nf)
        bv[nf] = *(const bf16x8*)((char*)sB + swz(wc * 64 + nf * 16 + l15, kbyte));
#pragma unroll
      for (int mf = 0; mf < 4; ++mf)
#pragma unroll
        for (int nf = 0; nf < 4; ++nf)
          acc[mf][nf] = __builtin_amdgcn_mfma_f32_16x16x32_bf16(
              av[mf], bv[nf], acc[mf][nf], 0, 0, 0);
    }
    __syncthreads();
  }

  const int r4 = (lane >> 4) << 2;
#pragma unroll
  for (int nf = 0; nf < 4; ++nf) {
    const int v = v0 + wc * 64 + nf * 16 + l15;
    const float bjv = bj[v];
#pragma unroll
    for (int mf = 0; mf < 4; ++mf) {
      const int u = wr * 64 + mf * 16 + r4;
      const size_t o = ((size_t)bt * 128 + u) * 1024 + v;
#pragma unroll
      for (int rr = 0; rr < 4; ++rr)
        out[o + (size_t)rr * 1024] = acc[mf][nf][rr] + bjv;
    }
  }
}

extern "C" void kernel_launch(void* const* d_in, const int* in_sizes, int n_in,
                              void* d_out, int out_size, void* d_ws, size_t ws_size,
                              hipStream_t stream) {
  const float* enc = (const float*)d_in[0];
  const float* pred = (const float*)d_in[1];
  const float* W_enc = (const float*)d_in[2];
  const float* b_enc = (const float*)d_in[3];
  const float* W_pred = (const float*)d_in[4];
  const float* b_pred = (const float*)d_in[5];
  const float* W_joint = (const float*)d_in[6];
  const float* b_joint = (const float*)d_in[7];
  float* out = (float*)d_out;

  char* ws = (char*)d_ws;
  float* f = (float*)ws;                                   // 2621440 B
  float* gbuf = (float*)(ws + 2621440);                    // 1310720 B
  u16* Wet = (u16*)(ws + 2621440 + 1310720);               // 655360 B
  u16* Wpt = (u16*)(ws + 2621440 + 1310720 + 655360);      // 655360 B
  u16* Wjt = (u16*)(ws + 2621440 + 1310720 + 2 * 655360);  // 1310720 B
  const size_t fixed = 2621440 + 1310720 + 2 * 655360 + 1310720;  // 6553600
  u16* joint = (u16*)(ws + fixed);

  transpose_cast_kernel<<<640, 256, 0, stream>>>(W_enc, Wet, 512, 640);
  transpose_cast_kernel<<<640, 256, 0, stream>>>(W_pred, Wpt, 512, 640);
  transpose_cast_kernel<<<1024, 256, 0, stream>>>(W_joint, Wjt, 640, 1024);

  linear_kernel<<<16 * 10, 256, 0, stream>>>(enc, Wet, b_enc, f);
  linear_kernel<<<8 * 10, 256, 0, stream>>>(pred, Wpt, b_pred, gbuf);

  const long TOTAL_M = 131072;
  long maxrows = ws_size > fixed ? (long)((ws_size - fixed) / 1280) : 0;
  maxrows &= ~255L;  // gemm256 needs multiples of 256 rows

  if (maxrows >= 16384) {
    (void)hipFuncSetAttribute((const void*)gemm256_kernel,
                              hipFuncAttributeMaxDynamicSharedMemorySize, 131072);
    long CH = maxrows >= TOTAL_M ? TOTAL_M : maxrows;
    for (long m0 = 0; m0 < TOTAL_M; m0 += CH) {
      long R = TOTAL_M - m0 < CH ? TOTAL_M - m0 : CH;
      int mtiles = (int)(R / 256);
      joint_kernel<<<(int)(R / 128) * 40, 256, 0, stream>>>(f, gbuf, joint, (int)m0);
      gemm256_kernel<<<mtiles * 4, 512, 131072, stream>>>(joint, Wjt, b_joint, out,
                                                          (int)m0, mtiles);
    }
  } else {
    fused_joint_kernel<<<dim3(1024, 4), 512, 0, stream>>>(f, gbuf, Wjt, b_joint, out);
  }
}

// Round 6
// 349.092 us; speedup vs baseline: 1.0528x; 1.0528x over previous
//
#include <hip/hip_runtime.h>
#include <hip/hip_bf16.h>
#include <stdint.h>

typedef unsigned short u16;
typedef __attribute__((ext_vector_type(8))) __bf16 bf16x8;
typedef __attribute__((ext_vector_type(4))) float f32x4;
typedef __attribute__((ext_vector_type(8))) unsigned short u16x8;
typedef __attribute__((ext_vector_type(4))) unsigned int u32x4;

static __device__ __forceinline__ u16 f2bf(float x) {
  __hip_bfloat16 h = __float2bfloat16(x);
  u16 u;
  __builtin_memcpy(&u, &h, 2);
  return u;
}

static __device__ __forceinline__ float fast_tanh(float x) {
  float e = __expf(2.0f * x);
  return 1.0f - 2.0f * __builtin_amdgcn_rcpf(e + 1.0f);
}

static __device__ __forceinline__ void gload_lds16(const void* g, void* l) {
  __builtin_amdgcn_global_load_lds(
      (const __attribute__((address_space(1))) unsigned int*)g,
      (__attribute__((address_space(3))) unsigned int*)l, 16, 0, 0);
}

// XOR swizzle for 128-B rows (reg-staged kernels)
static __device__ __forceinline__ int swz(int row, int byte_in_row) {
  return row * 128 + (byte_in_row ^ ((row & 7) << 4));
}

// ---------------------------------------------------------------------------
// Transpose + cast: out[n][k] (bf16) = in[k][n] (f32).  grid = N blocks.
// ---------------------------------------------------------------------------
__global__ __launch_bounds__(256) void transpose_cast_kernel(
    const float* __restrict__ in, u16* __restrict__ out, int K, int N) {
  int n = blockIdx.x;
  for (int k = threadIdx.x; k < K; k += 256) {
    out[(size_t)n * K + k] = f2bf(in[(size_t)k * N + n]);
  }
}

// ---------------------------------------------------------------------------
// Linear: out[M][640] = A[M][512] @ W + bias (W transposed bf16 [640][512]).
// ---------------------------------------------------------------------------
__global__ __launch_bounds__(256) void linear_kernel(
    const float* __restrict__ A, const u16* __restrict__ Wt,
    const float* __restrict__ bias, float* __restrict__ out) {
  __shared__ u16 sA[64 * 64];
  __shared__ u16 sB[64 * 64];
  const int t = threadIdx.x;
  const int bx = blockIdx.x;
  const int m0 = (bx / 10) * 64;
  const int n0 = (bx % 10) * 64;
  const int lane = t & 63, wid = t >> 6;
  const int wr = wid >> 1, wc = wid & 1;
  const int l15 = lane & 15, lk8 = (lane >> 4) << 3;

  const int srow = t >> 2;
  const int kc = (t & 3) << 4;

  f32x4 acc[2][2] = {};

  for (int k0 = 0; k0 < 512; k0 += 64) {
    {
      const float4* gp = (const float4*)(A + (size_t)(m0 + srow) * 512 + k0 + kc);
      u16 tmp[16];
#pragma unroll
      for (int i = 0; i < 4; ++i) {
        float4 v = gp[i];
        tmp[i * 4 + 0] = f2bf(v.x);
        tmp[i * 4 + 1] = f2bf(v.y);
        tmp[i * 4 + 2] = f2bf(v.z);
        tmp[i * 4 + 3] = f2bf(v.w);
      }
      *(u16x8*)((char*)sA + swz(srow, kc * 2)) = *(u16x8*)&tmp[0];
      *(u16x8*)((char*)sA + swz(srow, kc * 2 + 16)) = *(u16x8*)&tmp[8];
    }
    {
      const int off = (t & 3) << 5;
      const char* gsrc = (const char*)Wt + ((size_t)(n0 + srow) * 512 + k0) * 2 + off;
      u32x4 q0 = *(const u32x4*)gsrc;
      u32x4 q1 = *(const u32x4*)(gsrc + 16);
      *(u32x4*)((char*)sB + swz(srow, off)) = q0;
      *(u32x4*)((char*)sB + swz(srow, off + 16)) = q1;
    }
    __syncthreads();
#pragma unroll
    for (int kh = 0; kh < 2; ++kh) {
      const int kbyte = kh * 64 + lk8 * 2;
      bf16x8 av[2], bv[2];
#pragma unroll
      for (int mf = 0; mf < 2; ++mf)
        av[mf] = *(const bf16x8*)((char*)sA + swz(wr * 32 + mf * 16 + l15, kbyte));
#pragma unroll
      for (int nf = 0; nf < 2; ++nf)
        bv[nf] = *(const bf16x8*)((char*)sB + swz(wc * 32 + nf * 16 + l15, kbyte));
#pragma unroll
      for (int mf = 0; mf < 2; ++mf)
#pragma unroll
        for (int nf = 0; nf < 2; ++nf)
          acc[mf][nf] = __builtin_amdgcn_mfma_f32_16x16x32_bf16(
              av[mf], bv[nf], acc[mf][nf], 0, 0, 0);
    }
    __syncthreads();
  }

  const int r4 = (lane >> 4) << 2;
#pragma unroll
  for (int nf = 0; nf < 2; ++nf) {
    const int nc = n0 + wc * 32 + nf * 16 + l15;
    const float bjv = bias[nc];
#pragma unroll
    for (int mf = 0; mf < 2; ++mf) {
      const int mr = m0 + wr * 32 + mf * 16 + r4;
#pragma unroll
      for (int r = 0; r < 4; ++r)
        out[(size_t)(mr + r) * 640 + nc] = acc[mf][nf][r] + bjv;
    }
  }
}

// ---------------------------------------------------------------------------
// Joint materialize: joint[row][k] (bf16) = tanh(f[bt][k] + g[b][u][k])
// ---------------------------------------------------------------------------
__global__ __launch_bounds__(256) void joint_kernel(
    const float* __restrict__ f, const float* __restrict__ g,
    u16* __restrict__ joint, int m_base) {
  int idx = blockIdx.x * 256 + threadIdx.x;
  int row = idx / 80;
  int kc = (idx % 80) * 8;
  int m = m_base + row;
  int bt = m >> 7;
  int b = bt >> 8;
  int u = m & 127;
  const float4* fp = (const float4*)(f + (size_t)bt * 640 + kc);
  const float4* gp = (const float4*)(g + ((size_t)(b * 128 + u)) * 640 + kc);
  u16 tmp[8];
#pragma unroll
  for (int i = 0; i < 2; ++i) {
    float4 fv = fp[i];
    float4 gv = gp[i];
    tmp[i * 4 + 0] = f2bf(fast_tanh(fv.x + gv.x));
    tmp[i * 4 + 1] = f2bf(fast_tanh(fv.y + gv.y));
    tmp[i * 4 + 2] = f2bf(fast_tanh(fv.z + gv.z));
    tmp[i * 4 + 3] = f2bf(fast_tanh(fv.w + gv.w));
  }
  *(u16x8*)(joint + (size_t)row * 640 + kc) = *(u16x8*)&tmp[0];
}

// ---------------------------------------------------------------------------
// 256x256 8-phase-style GEMM (T1+T2+T3+T4+T5): out = joint @ Wjt^T + bias.
// BK=64, dbuf 2x64KiB LDS, 4 phases/K-tile x 16 MFMA, reads issued before
// the phase barrier, 1 half-tile stage (2 gload_lds) per phase, ONE counted
// s_waitcnt vmcnt(2) per K-tile at ph0 (never 0), trailing barrier per
// K-tile for the buffer swap.  512 threads, 8 waves (2Mx4N), wave 128x64.
// ---------------------------------------------------------------------------
__global__ __launch_bounds__(512, 2) void gemm256_kernel(
    const u16* __restrict__ A,    // [R][640] bf16 (chunk of joint)
    const u16* __restrict__ Bt,   // [1024][640] bf16 (W_joint^T)
    const float* __restrict__ bias,
    float* __restrict__ out,      // [131072][1024]
    int m_base, int mtiles) {
  extern __shared__ char smem[];  // dbuf[2] x (A 32K | B 32K) = 131072 B
  const int t = threadIdx.x;
  const int lane = t & 63, wid = t >> 6;

  // T1: m204 bijective XCD-chunked swizzle
  const int nwg = mtiles * 4;
  const int bid = blockIdx.x;
  const int q = nwg >> 3, r = nwg & 7;
  const int xcd = bid & 7, local = bid >> 3;
  const int wgid = (xcd < r ? xcd * (q + 1) : r * (q + 1) + (xcd - r) * q) + local;
  const int mt = wgid >> 2, nt = wgid & 3;

  const int wr = wid >> 2, wc = wid & 3;  // wave-tile rows wr*128, cols wc*64
  const int l15 = lane & 15;
  const int kb16 = (lane >> 4) << 4;      // fragment k-offset within kk-half
  const int rx = (l15 & 7) << 4;          // read-side swizzle xor (row&7)<<4

  // staging (validated in R4): 64-row chunks; wave wid covers rows wid*8..+7
  // of each chunk; source column inverse-swizzled so linear gload_lds dest
  // yields the XOR-swizzled layout (rule 21 / m173).
  const int scol = (((lane & 7) ^ (lane >> 3)) << 3);  // element offset
  const size_t rowsel = (size_t)(wid * 8 + (lane >> 3)) * 640 + scol;
  const u16* a0 = A + (size_t)(mt * 256) * 640 + rowsel;           // A rows 0..63
  const u16* a1 = a0 + (size_t)64 * 640;
  const u16* a2p = a0 + (size_t)128 * 640;
  const u16* a3 = a0 + (size_t)192 * 640;
  const u16* b0 = Bt + (size_t)(nt * 256) * 640 + rowsel;
  const u16* b1 = b0 + (size_t)64 * 640;
  const u16* b2p = b0 + (size_t)128 * 640;
  const u16* b3 = b0 + (size_t)192 * 640;
  const int ldst = wid * 1024;  // wave-uniform dest offset within 8-KiB chunk

  // half h of K-tile kt into dbuf base nb: h0=A[0:128), h1=A[128:256),
  // h2=B[0:128), h3=B[128:256).  Each = 2 chunk issues.
#define STAGE_HALF(kt, h, nb)                                               \
  do {                                                                      \
    const int ko_ = (kt) * 64;                                              \
    gload_lds16(((h) == 0 ? a0 : (h) == 1 ? a2p : (h) == 2 ? b0 : b2p) + ko_, \
                smem + (nb) + (h) * 16384 + ldst);                          \
    gload_lds16(((h) == 0 ? a1 : (h) == 1 ? a3 : (h) == 2 ? b1 : b3) + ko_, \
                smem + (nb) + (h) * 16384 + 8192 + ldst);                   \
  } while (0)

#define DSREAD_B(kkb)                                                       \
  _Pragma("unroll") for (int nf = 0; nf < 4; ++nf) bv[nf] =                 \
      *(const bf16x8*)(sB + (wc * 64 + nf * 16 + l15) * 128 +               \
                       (((kkb) + kb16) ^ rx));

#define DSREAD_A(mi0, kkb)                                                  \
  _Pragma("unroll") for (int i = 0; i < 4; ++i) av[i] =                     \
      *(const bf16x8*)(sA + (wr * 128 + ((mi0) + i) * 16 + l15) * 128 +     \
                       (((kkb) + kb16) ^ rx));

#define MFMA16(mi0)                                                         \
  __builtin_amdgcn_s_setprio(1);                                            \
  _Pragma("unroll") for (int i = 0; i < 4; ++i)                             \
  _Pragma("unroll") for (int nf = 0; nf < 4; ++nf)                          \
      acc[(mi0) + i][nf] = __builtin_amdgcn_mfma_f32_16x16x32_bf16(         \
          av[i], bv[nf], acc[(mi0) + i][nf], 0, 0, 0);                      \
  __builtin_amdgcn_s_setprio(0);

#define LGKM0()                                          \
  asm volatile("s_waitcnt lgkmcnt(0)" ::: "memory");     \
  __builtin_amdgcn_sched_barrier(0);

  f32x4 acc[8][4] = {};

  // prologue: stage all 4 halves of K-tile 0 into dbuf 0
  STAGE_HALF(0, 0, 0);
  STAGE_HALF(0, 1, 0);
  STAGE_HALF(0, 2, 0);
  STAGE_HALF(0, 3, 0);

  for (int tt = 0; tt < 10; ++tt) {
    const int cur = (tt & 1) << 16;
    const int nxt = cur ^ 65536;
    const int kt = (tt + 1 < 10) ? tt + 1 : 9;  // tail: dummy re-stage (L2-hot)
    const char* sA = smem + cur;
    const char* sB = smem + cur + 32768;
    bf16x8 av[4], bv[4];

    // ---- phase 0: certify tile tt, compute m0-3 x kk0 ----
    STAGE_HALF(kt, 0, nxt);
    asm volatile("s_waitcnt vmcnt(2)" ::: "memory");  // tile tt landed (own)
    __builtin_amdgcn_sched_barrier(0);
    __builtin_amdgcn_s_barrier();                     // cross-wave certify
    DSREAD_B(0)
    DSREAD_A(0, 0)
    LGKM0()
    MFMA16(0)

    // ---- phase 1: m4-7 x kk0 ----
    DSREAD_A(4, 0)
    STAGE_HALF(kt, 1, nxt);
    __builtin_amdgcn_s_barrier();
    LGKM0()
    MFMA16(4)

    // ---- phase 2: m0-3 x kk1 ----
    DSREAD_B(64)
    DSREAD_A(0, 64)
    STAGE_HALF(kt, 2, nxt);
    __builtin_amdgcn_s_barrier();
    LGKM0()
    MFMA16(0)

    // ---- phase 3: m4-7 x kk1 ----
    DSREAD_A(4, 64)
    STAGE_HALF(kt, 3, nxt);
    __builtin_amdgcn_s_barrier();
    LGKM0()
    MFMA16(4)
    __builtin_amdgcn_s_barrier();  // all waves done reading dbuf[cur]
  }
#undef STAGE_HALF
#undef DSREAD_B
#undef DSREAD_A
#undef MFMA16
#undef LGKM0

  // epilogue
  const int r4 = (lane >> 4) << 2;
#pragma unroll
  for (int nf = 0; nf < 4; ++nf) {
    const int v = nt * 256 + wc * 64 + nf * 16 + l15;
    const float bjv = bias[v];
#pragma unroll
    for (int mf = 0; mf < 8; ++mf) {
      const size_t m = (size_t)m_base + (size_t)mt * 256 + wr * 128 + mf * 16 + r4;
#pragma unroll
      for (int rr = 0; rr < 4; ++rr)
        out[(m + rr) * 1024 + v] = acc[mf][nf][rr] + bjv;
    }
  }
}

// ---------------------------------------------------------------------------
// Fallback (fused) if ws can't hold the joint buffer.
// ---------------------------------------------------------------------------
__global__ __launch_bounds__(512) void fused_joint_kernel(
    const float* __restrict__ f, const float* __restrict__ g,
    const u16* __restrict__ Wjt, const float* __restrict__ bj,
    float* __restrict__ out) {
  __shared__ u16 sA[128 * 64];
  __shared__ u16 sB[256 * 64];
  const int t = threadIdx.x;
  const int bt = blockIdx.x;
  const int b = bt >> 8;
  const int v0 = blockIdx.y << 8;
  const float* frow = f + (size_t)bt * 640;
  const float* gbase = g + (size_t)b * 128 * 640;

  const int lane = t & 63, wid = t >> 6;
  const int wr = wid >> 2, wc = wid & 3;
  const int l15 = lane & 15, lk8 = (lane >> 4) << 3;

  const int au = t >> 2;
  const int akc = (t & 3) << 4;
  const int bn = t >> 1;
  const int boff = (t & 1) << 6;

  f32x4 acc[4][4] = {};

  for (int k0 = 0; k0 < 640; k0 += 64) {
    {
      const float4* gp = (const float4*)(gbase + (size_t)au * 640 + k0 + akc);
      const float4* fp = (const float4*)(frow + k0 + akc);
      u16 tmp[16];
#pragma unroll
      for (int i = 0; i < 4; ++i) {
        float4 gv = gp[i];
        float4 fv = fp[i];
        tmp[i * 4 + 0] = f2bf(fast_tanh(gv.x + fv.x));
        tmp[i * 4 + 1] = f2bf(fast_tanh(gv.y + fv.y));
        tmp[i * 4 + 2] = f2bf(fast_tanh(gv.z + fv.z));
        tmp[i * 4 + 3] = f2bf(fast_tanh(gv.w + fv.w));
      }
      *(u16x8*)((char*)sA + swz(au, akc * 2)) = *(u16x8*)&tmp[0];
      *(u16x8*)((char*)sA + swz(au, akc * 2 + 16)) = *(u16x8*)&tmp[8];
    }
    {
      const char* gsrc = (const char*)Wjt + ((size_t)(v0 + bn) * 640 + k0) * 2 + boff;
#pragma unroll
      for (int i = 0; i < 4; ++i) {
        u32x4 qv = *(const u32x4*)(gsrc + i * 16);
        *(u32x4*)((char*)sB + swz(bn, boff + i * 16)) = qv;
      }
    }
    __syncthreads();
#pragma unroll
    for (int kh = 0; kh < 2; ++kh) {
      const int kbyte = kh * 64 + lk8 * 2;
      bf16x8 av[4], bv[4];
#pragma unroll
      for (int mf = 0; mf < 4; ++mf)
        av[mf] = *(const bf16x8*)((char*)sA + swz(wr * 64 + mf * 16 + l15, kbyte));
#pragma unroll
      for (int nf = 0; nf < 4; ++nf)
        bv[nf] = *(const bf16x8*)((char*)sB + swz(wc * 64 + nf * 16 + l15, kbyte));
#pragma unroll
      for (int mf = 0; mf < 4; ++mf)
#pragma unroll
        for (int nf = 0; nf < 4; ++nf)
          acc[mf][nf] = __builtin_amdgcn_mfma_f32_16x16x32_bf16(
              av[mf], bv[nf], acc[mf][nf], 0, 0, 0);
    }
    __syncthreads();
  }

  const int r4 = (lane >> 4) << 2;
#pragma unroll
  for (int nf = 0; nf < 4; ++nf) {
    const int v = v0 + wc * 64 + nf * 16 + l15;
    const float bjv = bj[v];
#pragma unroll
    for (int mf = 0; mf < 4; ++mf) {
      const int u = wr * 64 + mf * 16 + r4;
      const size_t o = ((size_t)bt * 128 + u) * 1024 + v;
#pragma unroll
      for (int rr = 0; rr < 4; ++rr)
        out[o + (size_t)rr * 1024] = acc[mf][nf][rr] + bjv;
    }
  }
}

extern "C" void kernel_launch(void* const* d_in, const int* in_sizes, int n_in,
                              void* d_out, int out_size, void* d_ws, size_t ws_size,
                              hipStream_t stream) {
  const float* enc = (const float*)d_in[0];
  const float* pred = (const float*)d_in[1];
  const float* W_enc = (const float*)d_in[2];
  const float* b_enc = (const float*)d_in[3];
  const float* W_pred = (const float*)d_in[4];
  const float* b_pred = (const float*)d_in[5];
  const float* W_joint = (const float*)d_in[6];
  const float* b_joint = (const float*)d_in[7];
  float* out = (float*)d_out;

  char* ws = (char*)d_ws;
  float* f = (float*)ws;                                   // 2621440 B
  float* gbuf = (float*)(ws + 2621440);                    // 1310720 B
  u16* Wet = (u16*)(ws + 2621440 + 1310720);               // 655360 B
  u16* Wpt = (u16*)(ws + 2621440 + 1310720 + 655360);      // 655360 B
  u16* Wjt = (u16*)(ws + 2621440 + 1310720 + 2 * 655360);  // 1310720 B
  const size_t fixed = 2621440 + 1310720 + 2 * 655360 + 1310720;  // 6553600
  u16* joint = (u16*)(ws + fixed);

  transpose_cast_kernel<<<640, 256, 0, stream>>>(W_enc, Wet, 512, 640);
  transpose_cast_kernel<<<640, 256, 0, stream>>>(W_pred, Wpt, 512, 640);
  transpose_cast_kernel<<<1024, 256, 0, stream>>>(W_joint, Wjt, 640, 1024);

  linear_kernel<<<16 * 10, 256, 0, stream>>>(enc, Wet, b_enc, f);
  linear_kernel<<<8 * 10, 256, 0, stream>>>(pred, Wpt, b_pred, gbuf);

  const long TOTAL_M = 131072;
  long maxrows = ws_size > fixed ? (long)((ws_size - fixed) / 1280) : 0;
  maxrows &= ~255L;  // gemm256 needs multiples of 256 rows

  if (maxrows >= 16384) {
    (void)hipFuncSetAttribute((const void*)gemm256_kernel,
                              hipFuncAttributeMaxDynamicSharedMemorySize, 131072);
    long CH = maxrows >= TOTAL_M ? TOTAL_M : maxrows;
    for (long m0 = 0; m0 < TOTAL_M; m0 += CH) {
      long R = TOTAL_M - m0 < CH ? TOTAL_M - m0 : CH;
      int mtiles = (int)(R / 256);
      joint_kernel<<<(int)(R / 128) * 40, 256, 0, stream>>>(f, gbuf, joint, (int)m0);
      gemm256_kernel<<<mtiles * 4, 512, 131072, stream>>>(joint, Wjt, b_joint, out,
                                                          (int)m0, mtiles);
    }
  } else {
    fused_joint_kernel<<<dim3(1024, 4), 512, 0, stream>>>(f, gbuf, Wjt, b_joint, out);
  }
}